// Round 6
// baseline (174.310 us; speedup 1.0000x reference)
//
#include <hip/hip_runtime.h>
#include <math.h>

// Problem constants (match reference)
#define B_SZ    2048
#define IN_DIM  256
#define N_RULES 128
#define OUT_DIM 64
#define D_DIM   32896          // (IN_DIM+1)*N_RULES
#define NBIG    8192           // N_RULES*OUT_DIM (n = r*64 + o)
#define KAQ     512            // Aq row: [x^2 (256) | x (256)]

typedef __attribute__((ext_vector_type(8))) short bf16x8;
typedef __attribute__((ext_vector_type(4))) float f32x4;

static __device__ __forceinline__ short f2bf(float f) {
    union { float f; unsigned u; } v; v.f = f;
    unsigned r = v.u + 0x7fffu + ((v.u >> 16) & 1u);   // RNE
    return (short)(r >> 16);
}
static __device__ __forceinline__ void gld_lds16(const short* g, short* l) {
    __builtin_amdgcn_global_load_lds((const __attribute__((address_space(1))) void*)g,
                                     (__attribute__((address_space(3))) void*)l, 16, 0, 0);
}

// ---------------------------------------------------------------------------
// abq: blocks [0,128):  Bq[r][0:256]=bf16(-s), Bq[r][256:512]=bf16(2cs), k2[r]
//      blocks [128,384): Aq[b][0:256]=bf16(x^2), Aq[b][256:512]=bf16(x)
//      block 0 also zeroes the 32 split-K completion counters (stream order
//      guarantees they are zero before fusedgemm increments them).
// ---------------------------------------------------------------------------
__global__ __launch_bounds__(256) void abq_kernel(const float* __restrict__ X,
                                                  const float* __restrict__ centers,
                                                  const float* __restrict__ sigmas,
                                                  short* __restrict__ Aq,
                                                  short* __restrict__ Bq,
                                                  float* __restrict__ k2,
                                                  int* __restrict__ cnt) {
    int bid = blockIdx.x, t = threadIdx.x;
    if (bid < 128) {
        if (bid == 0 && t < 32) cnt[t] = 0;
        int r = bid, i = t;
        float sgm = sigmas[i * N_RULES + r];
        float s   = 0.5f / (sgm * sgm) + 1e-8f;
        float c   = centers[i * N_RULES + r];
        Bq[(size_t)r * KAQ + i]       = f2bf(-s);
        Bq[(size_t)r * KAQ + 256 + i] = f2bf(2.0f * c * s);
        __shared__ float red[256];
        red[i] = c * c * s;
        __syncthreads();
        for (int st = 128; st > 0; st >>= 1) {
            if (i < st) red[i] += red[i + st];
            __syncthreads();
        }
        if (i == 0) k2[r] = red[0];
    } else {
        int gid = (bid - 128) * 256 + t;     // 0..65535
        int i0 = gid * 8;                    // 8 consecutive elems, same X row
        int b = i0 >> 8, k = i0 & 255;
        float4 x0 = *(const float4*)(X + i0);
        float4 x1 = *(const float4*)(X + i0 + 4);
        bf16x8 q, v;
        q[0] = f2bf(x0.x * x0.x); v[0] = f2bf(x0.x);
        q[1] = f2bf(x0.y * x0.y); v[1] = f2bf(x0.y);
        q[2] = f2bf(x0.z * x0.z); v[2] = f2bf(x0.z);
        q[3] = f2bf(x0.w * x0.w); v[3] = f2bf(x0.w);
        q[4] = f2bf(x1.x * x1.x); v[4] = f2bf(x1.x);
        q[5] = f2bf(x1.y * x1.y); v[5] = f2bf(x1.y);
        q[6] = f2bf(x1.z * x1.z); v[6] = f2bf(x1.z);
        q[7] = f2bf(x1.w * x1.w); v[7] = f2bf(x1.w);
        *(bf16x8*)(Aq + (size_t)b * KAQ + k)       = q;
        *(bf16x8*)(Aq + (size_t)b * KAQ + 256 + k) = v;
    }
}

// ---------------------------------------------------------------------------
// rawprep: blocks [0,128)   — rawgemm+softmax+LN stats (16 batch rows/block);
//          blocks [128,1152) — prep (vectorized): Bmat bf16(gamma*W), Gp/Cp
//          partials, wr tail. Independent work packed into one launch so the
//          128 rawsm blocks hide under prep's 1024 bandwidth-bound blocks.
// ---------------------------------------------------------------------------
__global__ __launch_bounds__(256) void rawprep_kernel(const short* __restrict__ Aq,
                                                      const short* __restrict__ Bq,
                                                      const float* __restrict__ k2,
                                                      const float* __restrict__ X,
                                                      const float* __restrict__ gamma,
                                                      const float* __restrict__ beta,
                                                      const float* __restrict__ W,
                                                      float* __restrict__ frs,
                                                      float* __restrict__ muA,
                                                      float* __restrict__ rstdA,
                                                      short* __restrict__ Bmat,
                                                      float* __restrict__ wr,
                                                      float* __restrict__ Gp,
                                                      float* __restrict__ Cp) {
    __shared__ float S[16][132];     // rawsm scores (pad 132)
    __shared__ float sg[256], sc_[256];
    int bid = blockIdx.x, t = threadIdx.x;

    if (bid < 128) {
        // ---- rawsm: M=16,N=128,K=512 MFMA + softmax + LN stats ----
        int wave = t >> 6, lane = t & 63;
        int lrow = lane & 15, kq = lane >> 4;
        int m0 = bid * 16;

        f32x4 acc[2];
#pragma unroll
        for (int ni = 0; ni < 2; ++ni)
#pragma unroll
            for (int j = 0; j < 4; ++j) acc[ni][j] = 0.0f;

        const short* Ar = Aq + (size_t)(m0 + lrow) * KAQ + kq * 8;
        const short* Br = Bq + (size_t)(wave * 32 + lrow) * KAQ + kq * 8;
#pragma unroll
        for (int kt = 0; kt < 16; ++kt) {
            bf16x8 a = *(const bf16x8*)(Ar + kt * 32);
#pragma unroll
            for (int ni = 0; ni < 2; ++ni) {
                bf16x8 b = *(const bf16x8*)(Br + (size_t)ni * 16 * KAQ + kt * 32);
                acc[ni] = __builtin_amdgcn_mfma_f32_16x16x32_bf16(a, b, acc[ni], 0, 0, 0);
            }
        }
#pragma unroll
        for (int ni = 0; ni < 2; ++ni) {
            int col = wave * 32 + ni * 16 + lrow;
            float kk2 = k2[col];
#pragma unroll
            for (int j = 0; j < 4; ++j)
                S[kq * 4 + j][col] = (acc[ni][j] - kk2) * (1.0f / 256.0f);
        }
        __syncthreads();

#pragma unroll
        for (int rr = 0; rr < 4; ++rr) {
            int row = wave * 4 + rr;
            int b = m0 + row;
            float v0 = S[row][lane];
            float v1 = S[row][64 + lane];
            float m = fmaxf(v0, v1);
#pragma unroll
            for (int off = 32; off >= 1; off >>= 1) m = fmaxf(m, __shfl_xor(m, off));
            float e0 = expf(v0 - m), e1 = expf(v1 - m);
            float ssum = e0 + e1;
#pragma unroll
            for (int off = 32; off >= 1; off >>= 1) ssum += __shfl_xor(ssum, off);
            float inv = 1.0f / ssum;
            e0 *= inv; e1 *= inv;
            frs[(size_t)b * N_RULES + lane]      = e0;
            frs[(size_t)b * N_RULES + 64 + lane] = e1;
            float q = e0 * e0 + e1 * e1;
            float4 xv = *(const float4*)(X + (size_t)b * IN_DIM + lane * 4);
            float sx  = xv.x + xv.y + xv.z + xv.w;
            float sx2 = xv.x * xv.x + xv.y * xv.y + xv.z * xv.z + xv.w * xv.w;
#pragma unroll
            for (int off = 32; off >= 1; off >>= 1) {
                q   += __shfl_xor(q, off);
                sx  += __shfl_xor(sx, off);
                sx2 += __shfl_xor(sx2, off);
            }
            if (lane == 0) {
                float mu  = (sx + 1.0f) / (float)D_DIM;
                float var = (sx2 + 1.0f) * q / (float)D_DIM - mu * mu;
                muA[b]   = mu;
                rstdA[b] = rsqrtf(var + 1e-5f);
            }
        }
    } else {
        // ---- prep: 8 consecutive d per thread (vectorized) ----
        int pid = bid - 128;
        int c = pid & 15, o = pid >> 4;
        const float* Wo = W + (size_t)o * D_DIM;
        int d0 = c * 2048 + t * 8;
        float4 w0 = *(const float4*)(Wo + d0);
        float4 w1 = *(const float4*)(Wo + d0 + 4);
        float4 g0 = *(const float4*)(gamma + d0);
        float4 g1 = *(const float4*)(gamma + d0 + 4);
        float4 b0 = *(const float4*)(beta + d0);
        float4 b1 = *(const float4*)(beta + d0 + 4);
        float p0 = g0.x * w0.x, p1 = g0.y * w0.y, p2 = g0.z * w0.z, p3 = g0.w * w0.w;
        float p4 = g1.x * w1.x, p5 = g1.y * w1.y, p6 = g1.z * w1.z, p7 = g1.w * w1.w;
        float g = p0 + p1 + p2 + p3 + p4 + p5 + p6 + p7;
        float cc = b0.x * w0.x + b0.y * w0.y + b0.z * w0.z + b0.w * w0.w
                 + b1.x * w1.x + b1.y * w1.y + b1.z * w1.z + b1.w * w1.w;
        bf16x8 pv;
        pv[0] = f2bf(p0); pv[1] = f2bf(p1); pv[2] = f2bf(p2); pv[3] = f2bf(p3);
        pv[4] = f2bf(p4); pv[5] = f2bf(p5); pv[6] = f2bf(p6); pv[7] = f2bf(p7);
        int r = d0 >> 8, k = d0 & 255;
        *(bf16x8*)(Bmat + (size_t)((r << 6) + o) * IN_DIM + k) = pv;
        if (c == 15 && t < 128) {
            int d = 32768 + t;
            float w  = Wo[d];
            float ga = gamma[d];
            float be = beta[d];
            g += ga * w; cc += be * w;
            wr[t * 64 + o] = ga * w;
        }
        sg[t] = g; sc_[t] = cc;
        __syncthreads();
        for (int s = 128; s > 0; s >>= 1) {
            if (t < s) { sg[t] += sg[t + s]; sc_[t] += sc_[t + s]; }
            __syncthreads();
        }
        if (t == 0) { Gp[c * 64 + o] = sg[0]; Cp[c * 64 + o] = sc_[0]; }
    }
}

// ---------------------------------------------------------------------------
// fused gemm1 + weighted reduce + split-K last-block epilogue.
//   Grid (16 nc, 32 m-tiles) = 512 blocks, 2/CU (8 waves/CU); bid%8 == nc%8
//   pins each nc's 256 KB Bmat slice + Aq rows to one XCD's L2.
//   kk-OUTER / nt-INNER with BK=128 (R3 structure — measured best): A-tile
//   staged once per kk half, B in 8 rounds, 4 live tile accumulators.
//   After full K, fold oacc += frs[row,r]*(acc[nt]+wr) in regs; wn=0/1
//   partials combined via LDS; fp32 slice P[nc][64rows][64].
//   Then: __threadfence (release) + per-m-tile serial counter; the LAST of
//   the 16 nc-blocks for this m-tile reduces the 16 P slices (L2/L3-warm)
//   and applies the LN affine + bias — the epi launch is eliminated.
// ---------------------------------------------------------------------------
__global__ __launch_bounds__(256, 2) void fusedgemm_kernel(const short* __restrict__ Aq,
                                                           const short* __restrict__ Bmat,
                                                           const float* __restrict__ frs,
                                                           const float* __restrict__ wr,
                                                           const float* __restrict__ muA,
                                                           const float* __restrict__ rstdA,
                                                           const float* __restrict__ Gp,
                                                           const float* __restrict__ Cp,
                                                           const float* __restrict__ bias,
                                                           float* __restrict__ P,
                                                           int* __restrict__ cnt,
                                                           float* __restrict__ out) {
    __shared__ __attribute__((aligned(16))) short As[64 * 128];   // 16 KB (per kk half)
    __shared__ __attribute__((aligned(16))) short Bs[128 * 128];  // 32 KB (per nt,kk)
    __shared__ float frs_s[64][9];    // stride 9: conflict-free broadcast reads
    __shared__ int lastflag;

    int nc = blockIdx.x;              // rules nc*8 .. nc*8+7
    int mt = blockIdx.y;
    int m0 = mt * 64;
    int t = threadIdx.x;
    int lane = t & 63, wave = t >> 6;
    int wm = wave >> 1, wn = wave & 1;
    int lrow = lane & 15, kq = lane >> 4;

    // stage frs for 64 rows x 8 rules (first k-loop sync covers the use)
    for (int u = t; u < 64 * 8; u += 256) {
        int row = u >> 3, rr = u & 7;
        frs_s[row][rr] = frs[(size_t)(m0 + row) * N_RULES + nc * 8 + rr];
    }

    f32x4 acc[4][2][4];               // [nt][mi][ni]
#pragma unroll
    for (int nt = 0; nt < 4; ++nt)
#pragma unroll
        for (int mi = 0; mi < 2; ++mi)
#pragma unroll
            for (int ni = 0; ni < 4; ++ni)
#pragma unroll
                for (int j = 0; j < 4; ++j) acc[nt][mi][ni][j] = 0.0f;

#pragma unroll
    for (int kk2 = 0; kk2 < 2; ++kk2) {
        int kk = kk2 * 128;
        // stage A tile (64 rows x 128 k) once for this kk: 4 sweeps.
        // XOR swizzle over 16 granules/row: linear LDS dest, inverse-swz src.
#pragma unroll
        for (int s = 0; s < 4; ++s) {
            int idx = s * 256 + t;
            int row = idx >> 4, gp = idx & 15;
            int kg = gp ^ (row & 15);
            gld_lds16(Aq + (size_t)(m0 + row) * KAQ + 256 + kk + kg * 8, As + idx * 8);
        }
#pragma unroll
        for (int nt = 0; nt < 4; ++nt) {
            int n0 = nc * 512 + nt * 128;
            // stage B tile (128 rows x 128 k): 8 sweeps
#pragma unroll
            for (int s = 0; s < 8; ++s) {
                int idx = s * 256 + t;
                int row = idx >> 4, gp = idx & 15;
                int kg = gp ^ (row & 15);
                gld_lds16(Bmat + (size_t)(n0 + row) * IN_DIM + kk + kg * 8, Bs + idx * 8);
            }
            __syncthreads();

#pragma unroll
            for (int ks = 0; ks < 4; ++ks) {
                bf16x8 a[2], bb[4];
#pragma unroll
                for (int mi = 0; mi < 2; ++mi) {
                    int row = wm * 32 + mi * 16 + lrow;
                    a[mi] = *(const bf16x8*)(As + row * 128 + (((ks * 4 + kq) ^ (row & 15)) * 8));
                }
#pragma unroll
                for (int ni = 0; ni < 4; ++ni) {
                    int row = wn * 64 + ni * 16 + lrow;
                    bb[ni] = *(const bf16x8*)(Bs + row * 128 + (((ks * 4 + kq) ^ (row & 15)) * 8));
                }
#pragma unroll
                for (int mi = 0; mi < 2; ++mi)
#pragma unroll
                    for (int ni = 0; ni < 4; ++ni)
                        acc[nt][mi][ni] = __builtin_amdgcn_mfma_f32_16x16x32_bf16(a[mi], bb[ni], acc[nt][mi][ni], 0, 0, 0);
            }
            __syncthreads();
        }
    }

    // fold frs weighting across the 4 tiles (registers only)
    f32x4 oacc[2][4];
#pragma unroll
    for (int mi = 0; mi < 2; ++mi)
#pragma unroll
        for (int ni = 0; ni < 4; ++ni)
#pragma unroll
            for (int j = 0; j < 4; ++j) oacc[mi][ni][j] = 0.0f;
#pragma unroll
    for (int nt = 0; nt < 4; ++nt) {
        int r  = nc * 8 + nt * 2 + wn;   // this wave's rule for tile nt
        int rr = nt * 2 + wn;
#pragma unroll
        for (int ni = 0; ni < 4; ++ni) {
            int o = ni * 16 + lrow;
            float wv = wr[(size_t)r * 64 + o];
#pragma unroll
            for (int mi = 0; mi < 2; ++mi) {
#pragma unroll
                for (int j = 0; j < 4; ++j) {
                    int row = wm * 32 + mi * 16 + kq * 4 + j;
                    oacc[mi][ni][j] += frs_s[row][rr] * (acc[nt][mi][ni][j] + wv);
                }
            }
        }
    }

    // combine wn=0/wn=1 partials (same (row,o)) via LDS; write P[nc][m0+row][o].
    float* redbuf = (float*)Bs;        // [64][68] fp32 = 17.4 KB (stride 68)
    if (wn == 1) {
#pragma unroll
        for (int mi = 0; mi < 2; ++mi)
#pragma unroll
            for (int ni = 0; ni < 4; ++ni)
#pragma unroll
                for (int j = 0; j < 4; ++j) {
                    int row = wm * 32 + mi * 16 + kq * 4 + j;
                    int o   = ni * 16 + lrow;
                    redbuf[row * 68 + o] = oacc[mi][ni][j];
                }
    }
    __syncthreads();
    if (wn == 0) {
        float* Pc = P + ((size_t)nc * B_SZ + m0) * 64;
#pragma unroll
        for (int mi = 0; mi < 2; ++mi)
#pragma unroll
            for (int ni = 0; ni < 4; ++ni)
#pragma unroll
                for (int j = 0; j < 4; ++j) {
                    int row = wm * 32 + mi * 16 + kq * 4 + j;
                    int o   = ni * 16 + lrow;
                    Pc[row * 64 + o] = oacc[mi][ni][j] + redbuf[row * 68 + o];
                }
    }

    // ---- split-K completion: last nc-block for this m-tile does the epilogue
    __threadfence();                     // release our P slice (device scope)
    __syncthreads();                     // all threads' writes+fences precede t0's atomic
    if (t == 0) lastflag = (atomicAdd(&cnt[mt], 1) == 15);
    __syncthreads();
    if (lastflag) {
        __threadfence();                 // acquire: see all 16 P slices
        int o = t & 63;
        float g = 0.f, cc = 0.f;
#pragma unroll
        for (int j = 0; j < 16; ++j) { g += Gp[j * 64 + o]; cc += Cp[j * 64 + o]; }
        cc += bias[o];
        for (int u = t >> 6; u < 64; u += 4) {
            int b = m0 + u;
            float S = 0.f;
#pragma unroll
            for (int p = 0; p < 16; ++p)
                S += P[((size_t)p * B_SZ + b) * 64 + o];
            out[(size_t)b * OUT_DIM + o] = rstdA[b] * (S - muA[b] * g) + cc;
        }
    }
}

// ---------------------------------------------------------------------------
extern "C" void kernel_launch(void* const* d_in, const int* in_sizes, int n_in,
                              void* d_out, int out_size, void* d_ws, size_t ws_size,
                              hipStream_t stream) {
    const float* X       = (const float*)d_in[0];
    const float* centers = (const float*)d_in[1];
    const float* sigmas  = (const float*)d_in[2];
    const float* gamma   = (const float*)d_in[3];
    const float* beta    = (const float*)d_in[4];
    const float* W       = (const float*)d_in[5];
    const float* bias    = (const float*)d_in[6];
    float* out = (float*)d_out;

    char* w = (char*)d_ws;
    short* Aq   = (short*)w; w += (size_t)B_SZ * KAQ * 2;           // 2 MB
    short* Bmat = (short*)w; w += (size_t)NBIG * IN_DIM * 2;        // 4 MB
    float* P    = (float*)w; w += (size_t)16 * B_SZ * 64 * 4;       // 8 MB
    short* Bq   = (short*)w; w += (size_t)N_RULES * KAQ * 2;        // 128 KB
    float* frs  = (float*)w; w += (size_t)B_SZ * N_RULES * 4;       // 1 MB
    float* wr   = (float*)w; w += (size_t)NBIG * 4;
    float* k2   = (float*)w; w += (size_t)N_RULES * 4;
    float* muA  = (float*)w; w += (size_t)B_SZ * 4;
    float* rstdA= (float*)w; w += (size_t)B_SZ * 4;
    float* Gp   = (float*)w; w += (size_t)16 * 64 * 4;
    float* Cp   = (float*)w; w += (size_t)16 * 64 * 4;
    int*   cnt  = (int*)w;   w += (size_t)32 * 4;

    abq_kernel<<<384, 256, 0, stream>>>(X, centers, sigmas, Aq, Bq, k2, cnt);
    rawprep_kernel<<<1152, 256, 0, stream>>>(Aq, Bq, k2, X, gamma, beta, W,
                                             frs, muA, rstdA, Bmat, wr, Gp, Cp);
    fusedgemm_kernel<<<dim3(16, 32), 256, 0, stream>>>(Aq, Bmat, frs, wr,
                                                       muA, rstdA, Gp, Cp, bias,
                                                       P, cnt, out);
}

// Round 7
// 107.689 us; speedup vs baseline: 1.6186x; 1.6186x over previous
//
#include <hip/hip_runtime.h>
#include <math.h>

// Problem constants (match reference)
#define B_SZ    2048
#define IN_DIM  256
#define N_RULES 128
#define OUT_DIM 64
#define D_DIM   32896          // (IN_DIM+1)*N_RULES
#define NBIG    8192           // N_RULES*OUT_DIM (n = r*64 + o)
#define KAQ     512            // Aq row: [x^2 (256) | x (256)]

typedef __attribute__((ext_vector_type(8))) short bf16x8;
typedef __attribute__((ext_vector_type(4))) float f32x4;
typedef __attribute__((ext_vector_type(16))) float f32x16;

static __device__ __forceinline__ short f2bf(float f) {
    union { float f; unsigned u; } v; v.f = f;
    unsigned r = v.u + 0x7fffu + ((v.u >> 16) & 1u);   // RNE
    return (short)(r >> 16);
}
static __device__ __forceinline__ void gld_lds16(const short* g, short* l) {
    __builtin_amdgcn_global_load_lds((const __attribute__((address_space(1))) void*)g,
                                     (__attribute__((address_space(3))) void*)l, 16, 0, 0);
}

// ---------------------------------------------------------------------------
// abq: blocks [0,128):  Bq[r][0:256]=bf16(-s), Bq[r][256:512]=bf16(2cs), k2[r]
//      blocks [128,384): Aq[b][0:256]=bf16(x^2), Aq[b][256:512]=bf16(x)
//      (vectorized: 8 elems/thread, float4 loads, bf16x8 stores)
// ---------------------------------------------------------------------------
__global__ __launch_bounds__(256) void abq_kernel(const float* __restrict__ X,
                                                  const float* __restrict__ centers,
                                                  const float* __restrict__ sigmas,
                                                  short* __restrict__ Aq,
                                                  short* __restrict__ Bq,
                                                  float* __restrict__ k2) {
    int bid = blockIdx.x, t = threadIdx.x;
    if (bid < 128) {
        int r = bid, i = t;
        float sgm = sigmas[i * N_RULES + r];
        float s   = 0.5f / (sgm * sgm) + 1e-8f;
        float c   = centers[i * N_RULES + r];
        Bq[(size_t)r * KAQ + i]       = f2bf(-s);
        Bq[(size_t)r * KAQ + 256 + i] = f2bf(2.0f * c * s);
        __shared__ float red[256];
        red[i] = c * c * s;
        __syncthreads();
        for (int st = 128; st > 0; st >>= 1) {
            if (i < st) red[i] += red[i + st];
            __syncthreads();
        }
        if (i == 0) k2[r] = red[0];
    } else {
        int gid = (bid - 128) * 256 + t;     // 0..65535
        int i0 = gid * 8;                    // 8 consecutive elems, same X row
        int b = i0 >> 8, k = i0 & 255;
        float4 x0 = *(const float4*)(X + i0);
        float4 x1 = *(const float4*)(X + i0 + 4);
        bf16x8 q, v;
        q[0] = f2bf(x0.x * x0.x); v[0] = f2bf(x0.x);
        q[1] = f2bf(x0.y * x0.y); v[1] = f2bf(x0.y);
        q[2] = f2bf(x0.z * x0.z); v[2] = f2bf(x0.z);
        q[3] = f2bf(x0.w * x0.w); v[3] = f2bf(x0.w);
        q[4] = f2bf(x1.x * x1.x); v[4] = f2bf(x1.x);
        q[5] = f2bf(x1.y * x1.y); v[5] = f2bf(x1.y);
        q[6] = f2bf(x1.z * x1.z); v[6] = f2bf(x1.z);
        q[7] = f2bf(x1.w * x1.w); v[7] = f2bf(x1.w);
        *(bf16x8*)(Aq + (size_t)b * KAQ + k)       = q;
        *(bf16x8*)(Aq + (size_t)b * KAQ + 256 + k) = v;
    }
}

// ---------------------------------------------------------------------------
// rawprep: blocks [0,128)   — rawgemm+softmax+LN stats (16 batch rows/block);
//          blocks [128,1152) — prep (vectorized): Bmat bf16(gamma*W), Gp/Cp
//          partials, wr tail. Independent work packed into one launch so the
//          128 rawsm blocks hide under prep's 1024 bandwidth-bound blocks.
// ---------------------------------------------------------------------------
__global__ __launch_bounds__(256) void rawprep_kernel(const short* __restrict__ Aq,
                                                      const short* __restrict__ Bq,
                                                      const float* __restrict__ k2,
                                                      const float* __restrict__ X,
                                                      const float* __restrict__ gamma,
                                                      const float* __restrict__ beta,
                                                      const float* __restrict__ W,
                                                      float* __restrict__ frs,
                                                      float* __restrict__ muA,
                                                      float* __restrict__ rstdA,
                                                      short* __restrict__ Bmat,
                                                      float* __restrict__ wr,
                                                      float* __restrict__ Gp,
                                                      float* __restrict__ Cp) {
    __shared__ float S[16][132];     // rawsm scores (pad 132)
    __shared__ float sg[256], sc_[256];
    int bid = blockIdx.x, t = threadIdx.x;

    if (bid < 128) {
        // ---- rawsm: M=16,N=128,K=512 MFMA + softmax + LN stats ----
        int wave = t >> 6, lane = t & 63;
        int lrow = lane & 15, kq = lane >> 4;
        int m0 = bid * 16;

        f32x4 acc[2];
#pragma unroll
        for (int ni = 0; ni < 2; ++ni)
#pragma unroll
            for (int j = 0; j < 4; ++j) acc[ni][j] = 0.0f;

        const short* Ar = Aq + (size_t)(m0 + lrow) * KAQ + kq * 8;
        const short* Br = Bq + (size_t)(wave * 32 + lrow) * KAQ + kq * 8;
#pragma unroll
        for (int kt = 0; kt < 16; ++kt) {
            bf16x8 a = *(const bf16x8*)(Ar + kt * 32);
#pragma unroll
            for (int ni = 0; ni < 2; ++ni) {
                bf16x8 b = *(const bf16x8*)(Br + (size_t)ni * 16 * KAQ + kt * 32);
                acc[ni] = __builtin_amdgcn_mfma_f32_16x16x32_bf16(a, b, acc[ni], 0, 0, 0);
            }
        }
#pragma unroll
        for (int ni = 0; ni < 2; ++ni) {
            int col = wave * 32 + ni * 16 + lrow;
            float kk2 = k2[col];
#pragma unroll
            for (int j = 0; j < 4; ++j)
                S[kq * 4 + j][col] = (acc[ni][j] - kk2) * (1.0f / 256.0f);
        }
        __syncthreads();

#pragma unroll
        for (int rr = 0; rr < 4; ++rr) {
            int row = wave * 4 + rr;
            int b = m0 + row;
            float v0 = S[row][lane];
            float v1 = S[row][64 + lane];
            float m = fmaxf(v0, v1);
#pragma unroll
            for (int off = 32; off >= 1; off >>= 1) m = fmaxf(m, __shfl_xor(m, off));
            float e0 = expf(v0 - m), e1 = expf(v1 - m);
            float ssum = e0 + e1;
#pragma unroll
            for (int off = 32; off >= 1; off >>= 1) ssum += __shfl_xor(ssum, off);
            float inv = 1.0f / ssum;
            e0 *= inv; e1 *= inv;
            frs[(size_t)b * N_RULES + lane]      = e0;
            frs[(size_t)b * N_RULES + 64 + lane] = e1;
            float q = e0 * e0 + e1 * e1;
            float4 xv = *(const float4*)(X + (size_t)b * IN_DIM + lane * 4);
            float sx  = xv.x + xv.y + xv.z + xv.w;
            float sx2 = xv.x * xv.x + xv.y * xv.y + xv.z * xv.z + xv.w * xv.w;
#pragma unroll
            for (int off = 32; off >= 1; off >>= 1) {
                q   += __shfl_xor(q, off);
                sx  += __shfl_xor(sx, off);
                sx2 += __shfl_xor(sx2, off);
            }
            if (lane == 0) {
                float mu  = (sx + 1.0f) / (float)D_DIM;
                float var = (sx2 + 1.0f) * q / (float)D_DIM - mu * mu;
                muA[b]   = mu;
                rstdA[b] = rsqrtf(var + 1e-5f);
            }
        }
    } else {
        // ---- prep: 8 consecutive d per thread (vectorized) ----
        int pid = bid - 128;
        int c = pid & 15, o = pid >> 4;
        const float* Wo = W + (size_t)o * D_DIM;
        int d0 = c * 2048 + t * 8;
        float4 w0 = *(const float4*)(Wo + d0);
        float4 w1 = *(const float4*)(Wo + d0 + 4);
        float4 g0 = *(const float4*)(gamma + d0);
        float4 g1 = *(const float4*)(gamma + d0 + 4);
        float4 b0 = *(const float4*)(beta + d0);
        float4 b1 = *(const float4*)(beta + d0 + 4);
        float p0 = g0.x * w0.x, p1 = g0.y * w0.y, p2 = g0.z * w0.z, p3 = g0.w * w0.w;
        float p4 = g1.x * w1.x, p5 = g1.y * w1.y, p6 = g1.z * w1.z, p7 = g1.w * w1.w;
        float g = p0 + p1 + p2 + p3 + p4 + p5 + p6 + p7;
        float cc = b0.x * w0.x + b0.y * w0.y + b0.z * w0.z + b0.w * w0.w
                 + b1.x * w1.x + b1.y * w1.y + b1.z * w1.z + b1.w * w1.w;
        bf16x8 pv;
        pv[0] = f2bf(p0); pv[1] = f2bf(p1); pv[2] = f2bf(p2); pv[3] = f2bf(p3);
        pv[4] = f2bf(p4); pv[5] = f2bf(p5); pv[6] = f2bf(p6); pv[7] = f2bf(p7);
        int r = d0 >> 8, k = d0 & 255;
        *(bf16x8*)(Bmat + (size_t)((r << 6) + o) * IN_DIM + k) = pv;
        if (c == 15 && t < 128) {
            int d = 32768 + t;
            float w  = Wo[d];
            float ga = gamma[d];
            float be = beta[d];
            g += ga * w; cc += be * w;
            wr[t * 64 + o] = ga * w;
        }
        sg[t] = g; sc_[t] = cc;
        __syncthreads();
        for (int s = 128; s > 0; s >>= 1) {
            if (t < s) { sg[t] += sg[t + s]; sc_[t] += sc_[t + s]; }
            __syncthreads();
        }
        if (t == 0) { Gp[c * 64 + o] = sg[0]; Cp[c * 64 + o] = sc_[0]; }
    }
}

// ---------------------------------------------------------------------------
// fused gemm1 + weighted reduce (T never materialized). R3 structure
// (kk-outer / nt-inner, BK=128, measured best) with 32x32x16 MFMA:
//   ~20% fewer MFMA pipe-cycles (8.07 cyc/32K FLOP vs 4.85/16K) and half the
//   MFMA instruction count — frees issue slots for staging VALU.
//   Per-wave quadrant = 32 rows (wm) x 64 cols (wn) = 1 m-tile x 2 n-tiles.
//   A/B fragment: row=lane&31, k=(lane>>5)*8+e (generalizes verified 16x16
//   pattern). C/D: col=lane&31, row=(reg&3)+8*(reg>>2)+4*(lane>>5) (m74).
//   VGPR control: each nt-tile is folded into oacc immediately after its
//   K-chunk (linearity: frs*(a1)+frs*(a2+wv) == frs*(a1+a2+wv)), so only
//   acc[2]+oacc[2] (64 regs) live -> keeps 3 blocks/CU (LDS 50.3 KB).
//   wn=0/1 partials combined via LDS; fp32 slice P[nc][64rows][64].
// ---------------------------------------------------------------------------
__global__ __launch_bounds__(256, 2) void fusedgemm_kernel(const short* __restrict__ Aq,
                                                           const short* __restrict__ Bmat,
                                                           const float* __restrict__ frs,
                                                           const float* __restrict__ wr,
                                                           float* __restrict__ P) {
    __shared__ __attribute__((aligned(16))) short As[64 * 128];   // 16 KB (per kk half)
    __shared__ __attribute__((aligned(16))) short Bs[128 * 128];  // 32 KB (per nt,kk)
    __shared__ float frs_s[64][9];    // stride 9: conflict-free broadcast reads

    int nc = blockIdx.x;              // rules nc*8 .. nc*8+7
    int m0 = blockIdx.y * 64;
    int t = threadIdx.x;
    int lane = t & 63, wave = t >> 6;
    int wm = wave >> 1, wn = wave & 1;
    int l31 = lane & 31, lhi = lane >> 5;

    // stage frs for 64 rows x 8 rules (first k-loop sync covers the use)
    for (int u = t; u < 64 * 8; u += 256) {
        int row = u >> 3, rr = u & 7;
        frs_s[row][rr] = frs[(size_t)(m0 + row) * N_RULES + nc * 8 + rr];
    }

    f32x16 acc[2], oacc[2];
#pragma unroll
    for (int ni = 0; ni < 2; ++ni)
#pragma unroll
        for (int j = 0; j < 16; ++j) { acc[ni][j] = 0.0f; oacc[ni][j] = 0.0f; }

#pragma unroll
    for (int kk2 = 0; kk2 < 2; ++kk2) {
        int kk = kk2 * 128;
        // stage A tile (64 rows x 128 k) once for this kk: 4 sweeps.
        // XOR swizzle over 16 granules/row: linear LDS dest, inverse-swz src.
#pragma unroll
        for (int s = 0; s < 4; ++s) {
            int idx = s * 256 + t;
            int row = idx >> 4, gp = idx & 15;
            int kg = gp ^ (row & 15);
            gld_lds16(Aq + (size_t)(m0 + row) * KAQ + 256 + kk + kg * 8, As + idx * 8);
        }
#pragma unroll
        for (int nt = 0; nt < 4; ++nt) {
            int n0 = nc * 512 + nt * 128;
            // stage B tile (128 rows x 128 k): 8 sweeps
#pragma unroll
            for (int s = 0; s < 8; ++s) {
                int idx = s * 256 + t;
                int row = idx >> 4, gp = idx & 15;
                int kg = gp ^ (row & 15);
                gld_lds16(Bmat + (size_t)(n0 + row) * IN_DIM + kk + kg * 8, Bs + idx * 8);
            }
            __syncthreads();

            // 8 K-steps of 16: granule g = ks*2 + lhi (16 granules per row)
            int arow = wm * 32 + l31;
#pragma unroll
            for (int ks = 0; ks < 8; ++ks) {
                int g = ks * 2 + lhi;
                bf16x8 a = *(const bf16x8*)(As + arow * 128 + ((g ^ (arow & 15)) * 8));
#pragma unroll
                for (int ni = 0; ni < 2; ++ni) {
                    int brow = wn * 64 + ni * 32 + l31;
                    bf16x8 b = *(const bf16x8*)(Bs + brow * 128 + ((g ^ (brow & 15)) * 8));
                    acc[ni] = __builtin_amdgcn_mfma_f32_32x32x16_bf16(a, b, acc[ni], 0, 0, 0);
                }
            }
            __syncthreads();

            // fold this nt's K-chunk into oacc (registers only); add wr once
            // (second half). frs*(a1) + frs*(a2+wv) == frs*(a1+a2+wv).
            int r  = nc * 8 + nt * 2 + wn;   // this wave's rule for tile nt
            int rr = nt * 2 + wn;
#pragma unroll
            for (int ni = 0; ni < 2; ++ni) {
                int o = ni * 32 + l31;
                float wv = (kk2 == 1) ? wr[(size_t)r * 64 + o] : 0.0f;
#pragma unroll
                for (int reg = 0; reg < 16; ++reg) {
                    int row = wm * 32 + (reg & 3) + 8 * (reg >> 2) + 4 * lhi;
                    oacc[ni][reg] += frs_s[row][rr] * (acc[ni][reg] + wv);
                    acc[ni][reg] = 0.0f;
                }
            }
        }
    }

    // combine wn=0/wn=1 partials (same (row,o)) via LDS; write P[nc][m0+row][o].
    float* redbuf = (float*)Bs;        // [64][68] fp32 = 17.4 KB (stride 68)
    if (wn == 1) {
#pragma unroll
        for (int ni = 0; ni < 2; ++ni)
#pragma unroll
            for (int reg = 0; reg < 16; ++reg) {
                int row = wm * 32 + (reg & 3) + 8 * (reg >> 2) + 4 * lhi;
                int o   = ni * 32 + l31;
                redbuf[row * 68 + o] = oacc[ni][reg];
            }
    }
    __syncthreads();
    if (wn == 0) {
        float* Pc = P + ((size_t)nc * B_SZ + m0) * 64;
#pragma unroll
        for (int ni = 0; ni < 2; ++ni)
#pragma unroll
            for (int reg = 0; reg < 16; ++reg) {
                int row = wm * 32 + (reg & 3) + 8 * (reg >> 2) + 4 * lhi;
                int o   = ni * 32 + l31;
                Pc[row * 64 + o] = oacc[ni][reg] + redbuf[row * 68 + o];
            }
    }
}

// ---------------------------------------------------------------------------
// epilogue: out[b,o] = rstd_b*( sum_p P[p][b][o] - mu_b*G[o] ) + C[o] + bias[o]
// 4 rows/block, 512 blocks.
// ---------------------------------------------------------------------------
__global__ void epi_kernel(const float* __restrict__ P, const float* __restrict__ Gp,
                           const float* __restrict__ Cp, const float* __restrict__ bias,
                           const float* __restrict__ muA, const float* __restrict__ rstdA,
                           float* __restrict__ out) {
    int t = threadIdx.x;
    int b = blockIdx.x * 4 + (t >> 6);
    int o = t & 63;
    float S = 0.f;
#pragma unroll
    for (int p = 0; p < 16; ++p)
        S += P[((size_t)p * B_SZ + b) * 64 + o];
    float g = 0.f, cc = 0.f;
#pragma unroll
    for (int j = 0; j < 16; ++j) { g += Gp[j * 64 + o]; cc += Cp[j * 64 + o]; }
    out[(size_t)b * OUT_DIM + o] = rstdA[b] * (S - muA[b] * g) + cc + bias[o];
}

// ---------------------------------------------------------------------------
extern "C" void kernel_launch(void* const* d_in, const int* in_sizes, int n_in,
                              void* d_out, int out_size, void* d_ws, size_t ws_size,
                              hipStream_t stream) {
    const float* X       = (const float*)d_in[0];
    const float* centers = (const float*)d_in[1];
    const float* sigmas  = (const float*)d_in[2];
    const float* gamma   = (const float*)d_in[3];
    const float* beta    = (const float*)d_in[4];
    const float* W       = (const float*)d_in[5];
    const float* bias    = (const float*)d_in[6];
    float* out = (float*)d_out;

    char* w = (char*)d_ws;
    short* Aq   = (short*)w; w += (size_t)B_SZ * KAQ * 2;           // 2 MB
    short* Bmat = (short*)w; w += (size_t)NBIG * IN_DIM * 2;        // 4 MB
    float* P    = (float*)w; w += (size_t)16 * B_SZ * 64 * 4;       // 8 MB
    short* Bq   = (short*)w; w += (size_t)N_RULES * KAQ * 2;        // 128 KB
    float* frs  = (float*)w; w += (size_t)B_SZ * N_RULES * 4;       // 1 MB
    float* wr   = (float*)w; w += (size_t)NBIG * 4;
    float* k2   = (float*)w; w += (size_t)N_RULES * 4;
    float* muA  = (float*)w; w += (size_t)B_SZ * 4;
    float* rstdA= (float*)w; w += (size_t)B_SZ * 4;
    float* Gp   = (float*)w; w += (size_t)16 * 64 * 4;
    float* Cp   = (float*)w; w += (size_t)16 * 64 * 4;

    abq_kernel<<<384, 256, 0, stream>>>(X, centers, sigmas, Aq, Bq, k2);
    rawprep_kernel<<<1152, 256, 0, stream>>>(Aq, Bq, k2, X, gamma, beta, W,
                                             frs, muA, rstdA, Bmat, wr, Gp, Cp);
    fusedgemm_kernel<<<dim3(16, 32), 256, 0, stream>>>(Aq, Bmat, frs, wr, P);
    epi_kernel<<<B_SZ / 4, 256, 0, stream>>>(P, Gp, Cp, bias, muA, rstdA, out);
}

// Round 8
// 102.989 us; speedup vs baseline: 1.6925x; 1.0456x over previous
//
#include <hip/hip_runtime.h>
#include <math.h>

// Problem constants (match reference)
#define B_SZ    2048
#define IN_DIM  256
#define N_RULES 128
#define OUT_DIM 64
#define D_DIM   32896          // (IN_DIM+1)*N_RULES
#define NBIG    8192           // N_RULES*OUT_DIM (n = r*64 + o)
#define KAQ     512            // Aq row: [x^2 (256) | x (256)]

typedef __attribute__((ext_vector_type(8))) short bf16x8;
typedef __attribute__((ext_vector_type(4))) float f32x4;

static __device__ __forceinline__ short f2bf(float f) {
    union { float f; unsigned u; } v; v.f = f;
    unsigned r = v.u + 0x7fffu + ((v.u >> 16) & 1u);   // RNE
    return (short)(r >> 16);
}
static __device__ __forceinline__ void gld_lds16(const short* g, short* l) {
    __builtin_amdgcn_global_load_lds((const __attribute__((address_space(1))) void*)g,
                                     (__attribute__((address_space(3))) void*)l, 16, 0, 0);
}

// ---------------------------------------------------------------------------
// abq: blocks [0,128):  Bq[r][0:256]=bf16(-s), Bq[r][256:512]=bf16(2cs), k2[r]
//      blocks [128,384): Aq[b][0:256]=bf16(x^2), Aq[b][256:512]=bf16(x)
//      (vectorized: 8 elems/thread, float4 loads, bf16x8 stores)
// ---------------------------------------------------------------------------
__global__ __launch_bounds__(256) void abq_kernel(const float* __restrict__ X,
                                                  const float* __restrict__ centers,
                                                  const float* __restrict__ sigmas,
                                                  short* __restrict__ Aq,
                                                  short* __restrict__ Bq,
                                                  float* __restrict__ k2) {
    int bid = blockIdx.x, t = threadIdx.x;
    if (bid < 128) {
        int r = bid, i = t;
        float sgm = sigmas[i * N_RULES + r];
        float s   = 0.5f / (sgm * sgm) + 1e-8f;
        float c   = centers[i * N_RULES + r];
        Bq[(size_t)r * KAQ + i]       = f2bf(-s);
        Bq[(size_t)r * KAQ + 256 + i] = f2bf(2.0f * c * s);
        __shared__ float red[256];
        red[i] = c * c * s;
        __syncthreads();
        for (int st = 128; st > 0; st >>= 1) {
            if (i < st) red[i] += red[i + st];
            __syncthreads();
        }
        if (i == 0) k2[r] = red[0];
    } else {
        int gid = (bid - 128) * 256 + t;     // 0..65535
        int i0 = gid * 8;                    // 8 consecutive elems, same X row
        int b = i0 >> 8, k = i0 & 255;
        float4 x0 = *(const float4*)(X + i0);
        float4 x1 = *(const float4*)(X + i0 + 4);
        bf16x8 q, v;
        q[0] = f2bf(x0.x * x0.x); v[0] = f2bf(x0.x);
        q[1] = f2bf(x0.y * x0.y); v[1] = f2bf(x0.y);
        q[2] = f2bf(x0.z * x0.z); v[2] = f2bf(x0.z);
        q[3] = f2bf(x0.w * x0.w); v[3] = f2bf(x0.w);
        q[4] = f2bf(x1.x * x1.x); v[4] = f2bf(x1.x);
        q[5] = f2bf(x1.y * x1.y); v[5] = f2bf(x1.y);
        q[6] = f2bf(x1.z * x1.z); v[6] = f2bf(x1.z);
        q[7] = f2bf(x1.w * x1.w); v[7] = f2bf(x1.w);
        *(bf16x8*)(Aq + (size_t)b * KAQ + k)       = q;
        *(bf16x8*)(Aq + (size_t)b * KAQ + 256 + k) = v;
    }
}

// ---------------------------------------------------------------------------
// rawprep: blocks [0,128)   — rawgemm+softmax+LN stats (16 batch rows/block);
//          blocks [128,1152) — prep (vectorized): Bmat bf16(gamma*W), Gp/Cp
//          partials, wr tail. Independent work packed into one launch so the
//          128 rawsm blocks hide under prep's 1024 bandwidth-bound blocks.
// ---------------------------------------------------------------------------
__global__ __launch_bounds__(256) void rawprep_kernel(const short* __restrict__ Aq,
                                                      const short* __restrict__ Bq,
                                                      const float* __restrict__ k2,
                                                      const float* __restrict__ X,
                                                      const float* __restrict__ gamma,
                                                      const float* __restrict__ beta,
                                                      const float* __restrict__ W,
                                                      float* __restrict__ frs,
                                                      float* __restrict__ muA,
                                                      float* __restrict__ rstdA,
                                                      short* __restrict__ Bmat,
                                                      float* __restrict__ wr,
                                                      float* __restrict__ Gp,
                                                      float* __restrict__ Cp) {
    __shared__ float S[16][132];     // rawsm scores (pad 132)
    __shared__ float sg[256], sc_[256];
    int bid = blockIdx.x, t = threadIdx.x;

    if (bid < 128) {
        // ---- rawsm: M=16,N=128,K=512 MFMA + softmax + LN stats ----
        int wave = t >> 6, lane = t & 63;
        int lrow = lane & 15, kq = lane >> 4;
        int m0 = bid * 16;

        f32x4 acc[2];
#pragma unroll
        for (int ni = 0; ni < 2; ++ni)
#pragma unroll
            for (int j = 0; j < 4; ++j) acc[ni][j] = 0.0f;

        const short* Ar = Aq + (size_t)(m0 + lrow) * KAQ + kq * 8;
        const short* Br = Bq + (size_t)(wave * 32 + lrow) * KAQ + kq * 8;
#pragma unroll
        for (int kt = 0; kt < 16; ++kt) {
            bf16x8 a = *(const bf16x8*)(Ar + kt * 32);
#pragma unroll
            for (int ni = 0; ni < 2; ++ni) {
                bf16x8 b = *(const bf16x8*)(Br + (size_t)ni * 16 * KAQ + kt * 32);
                acc[ni] = __builtin_amdgcn_mfma_f32_16x16x32_bf16(a, b, acc[ni], 0, 0, 0);
            }
        }
#pragma unroll
        for (int ni = 0; ni < 2; ++ni) {
            int col = wave * 32 + ni * 16 + lrow;
            float kk2 = k2[col];
#pragma unroll
            for (int j = 0; j < 4; ++j)
                S[kq * 4 + j][col] = (acc[ni][j] - kk2) * (1.0f / 256.0f);
        }
        __syncthreads();

#pragma unroll
        for (int rr = 0; rr < 4; ++rr) {
            int row = wave * 4 + rr;
            int b = m0 + row;
            float v0 = S[row][lane];
            float v1 = S[row][64 + lane];
            float m = fmaxf(v0, v1);
#pragma unroll
            for (int off = 32; off >= 1; off >>= 1) m = fmaxf(m, __shfl_xor(m, off));
            float e0 = expf(v0 - m), e1 = expf(v1 - m);
            float ssum = e0 + e1;
#pragma unroll
            for (int off = 32; off >= 1; off >>= 1) ssum += __shfl_xor(ssum, off);
            float inv = 1.0f / ssum;
            e0 *= inv; e1 *= inv;
            frs[(size_t)b * N_RULES + lane]      = e0;
            frs[(size_t)b * N_RULES + 64 + lane] = e1;
            float q = e0 * e0 + e1 * e1;
            float4 xv = *(const float4*)(X + (size_t)b * IN_DIM + lane * 4);
            float sx  = xv.x + xv.y + xv.z + xv.w;
            float sx2 = xv.x * xv.x + xv.y * xv.y + xv.z * xv.z + xv.w * xv.w;
#pragma unroll
            for (int off = 32; off >= 1; off >>= 1) {
                q   += __shfl_xor(q, off);
                sx  += __shfl_xor(sx, off);
                sx2 += __shfl_xor(sx2, off);
            }
            if (lane == 0) {
                float mu  = (sx + 1.0f) / (float)D_DIM;
                float var = (sx2 + 1.0f) * q / (float)D_DIM - mu * mu;
                muA[b]   = mu;
                rstdA[b] = rsqrtf(var + 1e-5f);
            }
        }
    } else {
        // ---- prep: 8 consecutive d per thread (vectorized) ----
        int pid = bid - 128;
        int c = pid & 15, o = pid >> 4;
        const float* Wo = W + (size_t)o * D_DIM;
        int d0 = c * 2048 + t * 8;
        float4 w0 = *(const float4*)(Wo + d0);
        float4 w1 = *(const float4*)(Wo + d0 + 4);
        float4 g0 = *(const float4*)(gamma + d0);
        float4 g1 = *(const float4*)(gamma + d0 + 4);
        float4 b0 = *(const float4*)(beta + d0);
        float4 b1 = *(const float4*)(beta + d0 + 4);
        float p0 = g0.x * w0.x, p1 = g0.y * w0.y, p2 = g0.z * w0.z, p3 = g0.w * w0.w;
        float p4 = g1.x * w1.x, p5 = g1.y * w1.y, p6 = g1.z * w1.z, p7 = g1.w * w1.w;
        float g = p0 + p1 + p2 + p3 + p4 + p5 + p6 + p7;
        float cc = b0.x * w0.x + b0.y * w0.y + b0.z * w0.z + b0.w * w0.w
                 + b1.x * w1.x + b1.y * w1.y + b1.z * w1.z + b1.w * w1.w;
        bf16x8 pv;
        pv[0] = f2bf(p0); pv[1] = f2bf(p1); pv[2] = f2bf(p2); pv[3] = f2bf(p3);
        pv[4] = f2bf(p4); pv[5] = f2bf(p5); pv[6] = f2bf(p6); pv[7] = f2bf(p7);
        int r = d0 >> 8, k = d0 & 255;
        *(bf16x8*)(Bmat + (size_t)((r << 6) + o) * IN_DIM + k) = pv;
        if (c == 15 && t < 128) {
            int d = 32768 + t;
            float w  = Wo[d];
            float ga = gamma[d];
            float be = beta[d];
            g += ga * w; cc += be * w;
            wr[t * 64 + o] = ga * w;
        }
        sg[t] = g; sc_[t] = cc;
        __syncthreads();
        for (int s = 128; s > 0; s >>= 1) {
            if (t < s) { sg[t] += sg[t + s]; sc_[t] += sc_[t + s]; }
            __syncthreads();
        }
        if (t == 0) { Gp[c * 64 + o] = sg[0]; Cp[c * 64 + o] = sc_[0]; }
    }
}

// ---------------------------------------------------------------------------
// fused gemm1 + weighted reduce (T never materialized).
//   Grid (16 nc, 32 m-tiles) = 512 blocks, 2/CU (8 waves/CU); bid%8 == nc%8
//   pins each nc's 256 KB Bmat slice + Aq rows to one XCD's L2.
//   kk-OUTER / nt-INNER with BK=128: the 64x128 A-tile is staged ONCE per kk
//   half (2 stagings total vs 16 in the BK=64 nt-outer layout) and the
//   barrier-drain rounds halve (16 -> 8). Cost: 4 live tile accumulators
//   (128 acc VGPRs) -> __launch_bounds__(256,2) keeps 2 blocks/CU.
//   After full K, fold: oacc += frs[row, r(nt,wn)] * (acc[nt] + wr) in regs;
//   wn=0/1 partials combined via LDS; one fp32 slice P[nc][64rows][64].
//   [R4-R7 lessons: asm-pipelining/2-phase/setprio = neutral-to-negative
//   (co-resident block already hides drains, m114); device-scope fences or
//   contended atomics = catastrophic (non-coherent XCD L2 writeback);
//   32x32x16 MFMA = -4.6us (kernel is stage-bound, not MFMA-pipe-bound).]
// ---------------------------------------------------------------------------
__global__ __launch_bounds__(256, 2) void fusedgemm_kernel(const short* __restrict__ Aq,
                                                           const short* __restrict__ Bmat,
                                                           const float* __restrict__ frs,
                                                           const float* __restrict__ wr,
                                                           float* __restrict__ P) {
    __shared__ __attribute__((aligned(16))) short As[64 * 128];   // 16 KB (per kk half)
    __shared__ __attribute__((aligned(16))) short Bs[128 * 128];  // 32 KB (per nt,kk)
    __shared__ float frs_s[64][9];    // stride 9: conflict-free broadcast reads

    int nc = blockIdx.x;              // rules nc*8 .. nc*8+7
    int m0 = blockIdx.y * 64;
    int t = threadIdx.x;
    int lane = t & 63, wave = t >> 6;
    int wm = wave >> 1, wn = wave & 1;
    int lrow = lane & 15, kq = lane >> 4;

    // stage frs for 64 rows x 8 rules (first k-loop sync covers the use)
    for (int u = t; u < 64 * 8; u += 256) {
        int row = u >> 3, rr = u & 7;
        frs_s[row][rr] = frs[(size_t)(m0 + row) * N_RULES + nc * 8 + rr];
    }

    f32x4 acc[4][2][4];               // [nt][mi][ni]
#pragma unroll
    for (int nt = 0; nt < 4; ++nt)
#pragma unroll
        for (int mi = 0; mi < 2; ++mi)
#pragma unroll
            for (int ni = 0; ni < 4; ++ni)
#pragma unroll
                for (int j = 0; j < 4; ++j) acc[nt][mi][ni][j] = 0.0f;

#pragma unroll
    for (int kk2 = 0; kk2 < 2; ++kk2) {
        int kk = kk2 * 128;
        // stage A tile (64 rows x 128 k) once for this kk: 4 sweeps.
        // XOR swizzle over 16 granules/row: linear LDS dest, inverse-swz src.
#pragma unroll
        for (int s = 0; s < 4; ++s) {
            int idx = s * 256 + t;
            int row = idx >> 4, gp = idx & 15;
            int kg = gp ^ (row & 15);
            gld_lds16(Aq + (size_t)(m0 + row) * KAQ + 256 + kk + kg * 8, As + idx * 8);
        }
#pragma unroll
        for (int nt = 0; nt < 4; ++nt) {
            int n0 = nc * 512 + nt * 128;
            // stage B tile (128 rows x 128 k): 8 sweeps
#pragma unroll
            for (int s = 0; s < 8; ++s) {
                int idx = s * 256 + t;
                int row = idx >> 4, gp = idx & 15;
                int kg = gp ^ (row & 15);
                gld_lds16(Bmat + (size_t)(n0 + row) * IN_DIM + kk + kg * 8, Bs + idx * 8);
            }
            __syncthreads();

#pragma unroll
            for (int ks = 0; ks < 4; ++ks) {
                bf16x8 a[2], bb[4];
#pragma unroll
                for (int mi = 0; mi < 2; ++mi) {
                    int row = wm * 32 + mi * 16 + lrow;
                    a[mi] = *(const bf16x8*)(As + row * 128 + (((ks * 4 + kq) ^ (row & 15)) * 8));
                }
#pragma unroll
                for (int ni = 0; ni < 4; ++ni) {
                    int row = wn * 64 + ni * 16 + lrow;
                    bb[ni] = *(const bf16x8*)(Bs + row * 128 + (((ks * 4 + kq) ^ (row & 15)) * 8));
                }
#pragma unroll
                for (int mi = 0; mi < 2; ++mi)
#pragma unroll
                    for (int ni = 0; ni < 4; ++ni)
                        acc[nt][mi][ni] = __builtin_amdgcn_mfma_f32_16x16x32_bf16(a[mi], bb[ni], acc[nt][mi][ni], 0, 0, 0);
            }
            __syncthreads();
        }
    }

    // fold frs weighting across the 4 tiles (registers only)
    f32x4 oacc[2][4];
#pragma unroll
    for (int mi = 0; mi < 2; ++mi)
#pragma unroll
        for (int ni = 0; ni < 4; ++ni)
#pragma unroll
            for (int j = 0; j < 4; ++j) oacc[mi][ni][j] = 0.0f;
#pragma unroll
    for (int nt = 0; nt < 4; ++nt) {
        int r  = nc * 8 + nt * 2 + wn;   // this wave's rule for tile nt
        int rr = nt * 2 + wn;
#pragma unroll
        for (int ni = 0; ni < 4; ++ni) {
            int o = ni * 16 + lrow;
            float wv = wr[(size_t)r * 64 + o];
#pragma unroll
            for (int mi = 0; mi < 2; ++mi) {
#pragma unroll
                for (int j = 0; j < 4; ++j) {
                    int row = wm * 32 + mi * 16 + kq * 4 + j;
                    oacc[mi][ni][j] += frs_s[row][rr] * (acc[nt][mi][ni][j] + wv);
                }
            }
        }
    }

    // combine wn=0/wn=1 partials (same (row,o)) via LDS; write P[nc][m0+row][o].
    float* redbuf = (float*)Bs;        // [64][68] fp32 = 17.4 KB (stride 68)
    if (wn == 1) {
#pragma unroll
        for (int mi = 0; mi < 2; ++mi)
#pragma unroll
            for (int ni = 0; ni < 4; ++ni)
#pragma unroll
                for (int j = 0; j < 4; ++j) {
                    int row = wm * 32 + mi * 16 + kq * 4 + j;
                    int o   = ni * 16 + lrow;
                    redbuf[row * 68 + o] = oacc[mi][ni][j];
                }
    }
    __syncthreads();
    if (wn == 0) {
        float* Pc = P + ((size_t)nc * B_SZ + m0) * 64;
#pragma unroll
        for (int mi = 0; mi < 2; ++mi)
#pragma unroll
            for (int ni = 0; ni < 4; ++ni)
#pragma unroll
                for (int j = 0; j < 4; ++j) {
                    int row = wm * 32 + mi * 16 + kq * 4 + j;
                    int o   = ni * 16 + lrow;
                    Pc[row * 64 + o] = oacc[mi][ni][j] + redbuf[row * 68 + o];
                }
    }
}

// ---------------------------------------------------------------------------
// epilogue: out[b,o] = rstd_b*( sum_p P[p][b][o] - mu_b*G[o] ) + C[o] + bias[o]
// 4 rows/block, 512 blocks.
// ---------------------------------------------------------------------------
__global__ void epi_kernel(const float* __restrict__ P, const float* __restrict__ Gp,
                           const float* __restrict__ Cp, const float* __restrict__ bias,
                           const float* __restrict__ muA, const float* __restrict__ rstdA,
                           float* __restrict__ out) {
    int t = threadIdx.x;
    int b = blockIdx.x * 4 + (t >> 6);
    int o = t & 63;
    float S = 0.f;
#pragma unroll
    for (int p = 0; p < 16; ++p)
        S += P[((size_t)p * B_SZ + b) * 64 + o];
    float g = 0.f, cc = 0.f;
#pragma unroll
    for (int j = 0; j < 16; ++j) { g += Gp[j * 64 + o]; cc += Cp[j * 64 + o]; }
    out[(size_t)b * OUT_DIM + o] = rstdA[b] * (S - muA[b] * g) + cc + bias[o];
}

// ---------------------------------------------------------------------------
extern "C" void kernel_launch(void* const* d_in, const int* in_sizes, int n_in,
                              void* d_out, int out_size, void* d_ws, size_t ws_size,
                              hipStream_t stream) {
    const float* X       = (const float*)d_in[0];
    const float* centers = (const float*)d_in[1];
    const float* sigmas  = (const float*)d_in[2];
    const float* gamma   = (const float*)d_in[3];
    const float* beta    = (const float*)d_in[4];
    const float* W       = (const float*)d_in[5];
    const float* bias    = (const float*)d_in[6];
    float* out = (float*)d_out;

    char* w = (char*)d_ws;
    short* Aq   = (short*)w; w += (size_t)B_SZ * KAQ * 2;           // 2 MB
    short* Bmat = (short*)w; w += (size_t)NBIG * IN_DIM * 2;        // 4 MB
    float* P    = (float*)w; w += (size_t)16 * B_SZ * 64 * 4;       // 8 MB
    short* Bq   = (short*)w; w += (size_t)N_RULES * KAQ * 2;        // 128 KB
    float* frs  = (float*)w; w += (size_t)B_SZ * N_RULES * 4;       // 1 MB
    float* wr   = (float*)w; w += (size_t)NBIG * 4;
    float* k2   = (float*)w; w += (size_t)N_RULES * 4;
    float* muA  = (float*)w; w += (size_t)B_SZ * 4;
    float* rstdA= (float*)w; w += (size_t)B_SZ * 4;
    float* Gp   = (float*)w; w += (size_t)16 * 64 * 4;
    float* Cp   = (float*)w; w += (size_t)16 * 64 * 4;

    abq_kernel<<<384, 256, 0, stream>>>(X, centers, sigmas, Aq, Bq, k2);
    rawprep_kernel<<<1152, 256, 0, stream>>>(Aq, Bq, k2, X, gamma, beta, W,
                                             frs, muA, rstdA, Bmat, wr, Gp, Cp);
    fusedgemm_kernel<<<dim3(16, 32), 256, 0, stream>>>(Aq, Bmat, frs, wr, P);
    epi_kernel<<<B_SZ / 4, 256, 0, stream>>>(P, Gp, Cp, bias, muA, rstdA, out);
}